// Round 1
// baseline (134.373 us; speedup 1.0000x reference)
//
#include <hip/hip_runtime.h>
#include <cstddef>

#define CTXDIM 256
#define RANK 8
#define KW 7
#define SCALE 0.17677669529663687f
#define NPIX 16384
#define PLANE16 (NPIX * 128)   // elems per fp16 qkv plane
#define AH 14                  // attn halo rows = cols (8 + 6)
#define ANH 196                // 14*14
#define KST 40                 // fp16 LDS stride per halo pixel (80 B)
#define WSTRIDE 136            // fp16 LDS tile stride for GEMM staging

typedef _Float16 half8 __attribute__((ext_vector_type(8)));
typedef _Float16 half2_t __attribute__((ext_vector_type(2)));
typedef float floatx4 __attribute__((ext_vector_type(4)));

#if defined(__has_builtin)
#if __has_builtin(__builtin_amdgcn_fdot2)
#define HAVE_FDOT2 1
#endif
#endif

struct Params {
  const float *x, *ctx, *Wqkv, *bqkv, *A, *Blora, *Vlora;
  const float *g1w, *g1b, *g2w, *g2b, *Wproj, *bproj;
  float* out;
  _Float16* qkv16;   // planar fp16 [3][N][128]
  _Float16* at16;    // attention output fp16 [N][128]
};

// ---- cal[b][r] = alpha_b * (ctx[b] @ Blora)[r]; wave b handles batch b ----
__device__ __forceinline__ void compute_cal(const Params& p, int tid,
                                            float* cal_s) {
  const int b = tid >> 6, lane = tid & 63;
  const float c0 = p.ctx[b * CTXDIM + lane];
  const float c1 = p.ctx[b * CTXDIM + 64 + lane];
  const float c2 = p.ctx[b * CTXDIM + 128 + lane];
  const float c3 = p.ctx[b * CTXDIM + 192 + lane];
  float cp[RANK];
#pragma unroll
  for (int r = 0; r < RANK; ++r) {
    float q = c0 * p.Blora[lane * RANK + r] + c1 * p.Blora[(64 + lane) * RANK + r] +
              c2 * p.Blora[(128 + lane) * RANK + r] + c3 * p.Blora[(192 + lane) * RANK + r];
#pragma unroll
    for (int s = 32; s; s >>= 1) q += __shfl_xor(q, s, 64);
    cp[r] = q;
  }
  float gacc = 0.f;
#pragma unroll
  for (int h = 0; h < 16; ++h) {
    float q = c0 * p.g1w[h * CTXDIM + lane] + c1 * p.g1w[h * CTXDIM + 64 + lane] +
              c2 * p.g1w[h * CTXDIM + 128 + lane] + c3 * p.g1w[h * CTXDIM + 192 + lane];
#pragma unroll
    for (int s = 32; s; s >>= 1) q += __shfl_xor(q, s, 64);
    gacc += fmaxf(q + p.g1b[h], 0.f) * p.g2w[h];
  }
  if (lane == 0) {
    const float alpha = 1.f / (1.f + __expf(-(gacc + p.g2b[0])));
#pragma unroll
    for (int r = 0; r < RANK; ++r) cal_s[b * RANK + r] = alpha * cp[r];
  }
}

// ---- stage 64 fp32 rows (row stride 128) -> LDS fp16 [64][WSTRIDE] ----
__device__ __forceinline__ void stage_rows_f16(const float* __restrict__ src,
                                               _Float16* dst, int tid) {
  const int row = tid >> 2;
  const int c0 = (tid & 3) * 32;
  const float* sp = src + (size_t)row * 128 + c0;
  _Float16* dp = dst + row * WSTRIDE + c0;
#pragma unroll
  for (int i = 0; i < 4; ++i) {
    const float4 a = *(const float4*)(sp + i * 8);
    const float4 b = *(const float4*)(sp + i * 8 + 4);
    half8 o;
    o[0] = (_Float16)a.x; o[1] = (_Float16)a.y;
    o[2] = (_Float16)a.z; o[3] = (_Float16)a.w;
    o[4] = (_Float16)b.x; o[5] = (_Float16)b.y;
    o[6] = (_Float16)b.z; o[7] = (_Float16)b.w;
    *(half8*)(dp + i * 8) = o;
  }
}

// fp32 accumulate of an 8-wide fp16 dot product
__device__ __forceinline__ float dot8(half8 a, half8 b, float acc) {
#ifdef HAVE_FDOT2
#pragma unroll
  for (int e = 0; e < 4; ++e) {
    half2_t qa = {a[2 * e], a[2 * e + 1]};
    half2_t kb = {b[2 * e], b[2 * e + 1]};
    acc = __builtin_amdgcn_fdot2(qa, kb, acc, false);
  }
#else
#pragma unroll
  for (int e = 0; e < 8; ++e)
    acc = fmaf((float)a[e], (float)b[e], acc);
#endif
  return acc;
}

// ---------------------------------------------------------------------------
// K1: QKV GEMM, block-local prep.  Grid (64, 2, 4): block (bx, byg, z) stages
// its 64-row x-tile ONCE, then loops 3 n-tiles (byg*3+i)*64: fold Weff rows
// into LDS fp16 -> MFMA -> planar fp16 write.  x L2 reads drop 6x -> 2x;
// identical fp16 rounding path => qkv16 bit-identical to R10.
// ---------------------------------------------------------------------------
__global__ __launch_bounds__(256) void gemm1_kernel(Params p) {
  __shared__ __align__(16) _Float16 xs[64 * WSTRIDE];
  __shared__ __align__(16) _Float16 wsh[64 * WSTRIDE];
  __shared__ float cal_s[32];
  const int tid = threadIdx.x;
  const int bx = blockIdx.x, byg = blockIdx.y, z = blockIdx.z;
  const int m0 = z * 4096 + bx * 64;

  compute_cal(p, tid, cal_s);
  stage_rows_f16(p.x + (size_t)m0 * 128, xs, tid);
  __syncthreads();

  const int lane = tid & 63;
  const int w = tid >> 6;
  const int r = lane & 15;
  const int quad = lane >> 4;
  const int k = tid & 127;
  const int hgrp = tid >> 7;
  const float4 a0 = *(const float4*)&p.A[k * RANK];
  const float4 a1 = *(const float4*)&p.A[k * RANK + 4];
  const float* cb = &cal_s[z * RANK];
  const float c0 = cb[0], c1 = cb[1], c2 = cb[2], c3 = cb[3];
  const float c4 = cb[4], c5 = cb[5], c6 = cb[6], c7 = cb[7];

  for (int i = 0; i < 3; ++i) {
    const int n0 = (byg * 3 + i) * 64;

    // fold Weff rows n0..n0+63 into wsh (fp16)
#pragma unroll
    for (int rr = 0; rr < 32; ++rr) {
      const int row = hgrp * 32 + rr;
      const int o = n0 + row;
      const float4 v0 = *(const float4*)&p.Vlora[o * RANK];
      const float4 v1 = *(const float4*)&p.Vlora[o * RANK + 4];
      float d = a0.x * v0.x * c0;
      d = fmaf(a0.y * v0.y, c1, d);
      d = fmaf(a0.z * v0.z, c2, d);
      d = fmaf(a0.w * v0.w, c3, d);
      d = fmaf(a1.x * v1.x, c4, d);
      d = fmaf(a1.y * v1.y, c5, d);
      d = fmaf(a1.z * v1.z, c6, d);
      d = fmaf(a1.w * v1.w, c7, d);
      wsh[row * WSTRIDE + k] = (_Float16)(p.Wqkv[o * 128 + k] + d);
    }
    __syncthreads();

    const _Float16* ap = xs + (w * 16 + r) * WSTRIDE + quad * 8;
    const _Float16* bp = wsh + r * WSTRIDE + quad * 8;
    floatx4 acc0 = {0.f, 0.f, 0.f, 0.f};
    floatx4 acc1 = acc0, acc2 = acc0, acc3 = acc0;
#pragma unroll
    for (int kc = 0; kc < 4; ++kc) {
      const half8 a  = *(const half8*)(ap + kc * 32);
      const half8 b0 = *(const half8*)(bp + kc * 32);
      const half8 b1 = *(const half8*)(bp + 16 * WSTRIDE + kc * 32);
      const half8 b2 = *(const half8*)(bp + 32 * WSTRIDE + kc * 32);
      const half8 b3 = *(const half8*)(bp + 48 * WSTRIDE + kc * 32);
      acc0 = __builtin_amdgcn_mfma_f32_16x16x32_f16(a, b0, acc0, 0, 0, 0);
      acc1 = __builtin_amdgcn_mfma_f32_16x16x32_f16(a, b1, acc1, 0, 0, 0);
      acc2 = __builtin_amdgcn_mfma_f32_16x16x32_f16(a, b2, acc2, 0, 0, 0);
      acc3 = __builtin_amdgcn_mfma_f32_16x16x32_f16(a, b3, acc3, 0, 0, 0);
    }

    const int mbase = m0 + w * 16 + quad * 4;
    floatx4 accs[4] = {acc0, acc1, acc2, acc3};
#pragma unroll
    for (int nt = 0; nt < 4; ++nt) {
      const int ncol = n0 + nt * 16 + r;
      const float bv = p.bqkv[ncol];
      _Float16* cp = p.qkv16 + (size_t)(ncol >> 7) * PLANE16 +
                     (size_t)mbase * 128 + (ncol & 127);
#pragma unroll
      for (int reg = 0; reg < 4; ++reg)
        cp[(size_t)reg * 128] = (_Float16)(accs[nt][reg] + bv);
    }
    if (i != 2) __syncthreads();   // protect wsh before next fold
  }
}

// ---------------------------------------------------------------------------
// K2: neighborhood attention, OFFSET-SPLIT layout.
// Block = (b, ti, tj, h): 8x8 pixel tile, one head; 1024 blocks, 4/CU.
// 4 threads/pixel, but each thread owns ~12 of the 49 window offsets and
// computes FULL 32-dim dots for them (16 fdot2, ZERO shuffles per logit).
// Softmax: per-thread online max/sum over own offsets + 2 shuffles once
// (49 exps per pixel-head, was 196).  PV: 32-dim fp32 partial per thread,
// folded across the quartet with a 24-shuffle xor-2/xor-1 butterfly.
// Same staging, same LDS bytes; per-wave cross-lane ops 98 -> 28.
// ---------------------------------------------------------------------------
__global__ __launch_bounds__(256) void attn_kernel(Params p) {
  __shared__ __align__(16) _Float16 ks16[ANH * KST];
  __shared__ __align__(16) _Float16 vs16[ANH * KST];

  const int bid = blockIdx.x;        // [0,1024)
  const int h  = bid & 3;
  const int tj = (bid >> 2) & 7;
  const int ti = (bid >> 5) & 7;
  const int b  = bid >> 8;
  const int tid = threadIdx.x;

  const _Float16* kpl = p.qkv16 + PLANE16;
  const _Float16* vpl = p.qkv16 + 2 * (size_t)PLANE16;

  // ---- per-thread mapping + hoisted full-32-dim q load (overlaps staging) ----
  const int pix = tid >> 2;          // 0..63
  const int qtr = tid & 3;           // offset-residue class (owns s % 4 == qtr)
  const int pi = pix >> 3;
  const int pj = pix & 7;
  const int n = b * 4096 + (ti * 8 + pi) * 64 + tj * 8 + pj;
  const _Float16* qp = p.qkv16 + (size_t)n * 128 + h * 32;
  const half8 q0 = *(const half8*)(qp);
  const half8 q1 = *(const half8*)(qp + 8);
  const half8 q2 = *(const half8*)(qp + 16);
  const half8 q3 = *(const half8*)(qp + 24);

  // ---- stage K and V halos (196 pixels x 32 fp16 dims each) ----
  const int i0 = ti * 8 - 3;
  const int j0 = tj * 8 - 3;
#pragma unroll
  for (int it = 0; it < 4; ++it) {
    const int s = tid + it * 256;     // half8 slot, [0,784)
    if (s < ANH * 4) {
      const int pp = s >> 2;
      const int d8 = (s & 3) * 8;
      const int hr = pp / AH;
      const int hc = pp - hr * AH;
      const int ii = i0 + hr;
      const int jj = j0 + hc;
      half8 kv = {0, 0, 0, 0, 0, 0, 0, 0};
      half8 vv = {0, 0, 0, 0, 0, 0, 0, 0};
      if ((unsigned)ii < 64u && (unsigned)jj < 64u) {
        const size_t g = (size_t)(b * 4096 + ii * 64 + jj) * 128 + h * 32 + d8;
        kv = *(const half8*)(kpl + g);
        vv = *(const half8*)(vpl + g);
      }
      *(half8*)&ks16[pp * KST + d8] = kv;
      *(half8*)&vs16[pp * KST + d8] = vv;
    }
  }
  __syncthreads();

  // ---- logits for own offsets s = qtr, qtr+4, ... (13 for qtr 0, else 12) ----
  float l[13];
  float mx = -1e30f;
  {
    int di = 0, dj = qtr;
#pragma unroll
    for (int it = 0; it < 13; ++it) {
      if (it < 12 || qtr == 0) {
        const int hp = (pi + di) * AH + (pj + dj);
        const _Float16* kr = &ks16[hp * KST];
        const half8 k0 = *(const half8*)(kr);
        const half8 k1 = *(const half8*)(kr + 8);
        const half8 k2 = *(const half8*)(kr + 16);
        const half8 k3 = *(const half8*)(kr + 24);
        float pr = 0.f;
        pr = dot8(q0, k0, pr);
        pr = dot8(q1, k1, pr);
        pr = dot8(q2, k2, pr);
        pr = dot8(q3, k3, pr);
        const float lv = pr * SCALE;
        l[it] = lv;
        mx = fmaxf(mx, lv);
      }
      dj += 4; if (dj >= KW) { dj -= KW; ++di; }
    }
  }
  // combine max across the 4 offset-classes of this pixel-head
  mx = fmaxf(mx, __shfl_xor(mx, 1, 64));
  mx = fmaxf(mx, __shfl_xor(mx, 2, 64));

  float sum = 0.f;
#pragma unroll
  for (int it = 0; it < 13; ++it) {
    if (it < 12 || qtr == 0) {
      const float w = __expf(l[it] - mx);
      l[it] = w;
      sum += w;
    }
  }
  sum += __shfl_xor(sum, 1, 64);
  sum += __shfl_xor(sum, 2, 64);
  const float inv = 1.f / sum;

  // ---- PV: 32-dim fp32 partial over own offsets ----
  float o[32];
#pragma unroll
  for (int e = 0; e < 32; ++e) o[e] = 0.f;
  {
    int di = 0, dj = qtr;
#pragma unroll
    for (int it = 0; it < 13; ++it) {
      if (it < 12 || qtr == 0) {
        const int hp = (pi + di) * AH + (pj + dj);
        const _Float16* vr = &vs16[hp * KST];
        const float w = l[it];
        const half8 v0 = *(const half8*)(vr);
        const half8 v1 = *(const half8*)(vr + 8);
        const half8 v2 = *(const half8*)(vr + 16);
        const half8 v3 = *(const half8*)(vr + 24);
#pragma unroll
        for (int e = 0; e < 8; ++e) {
          o[e]      = fmaf(w, (float)v0[e], o[e]);
          o[8 + e]  = fmaf(w, (float)v1[e], o[8 + e]);
          o[16 + e] = fmaf(w, (float)v2[e], o[16 + e]);
          o[24 + e] = fmaf(w, (float)v3[e], o[24 + e]);
        }
      }
      dj += 4; if (dj >= KW) { dj -= KW; ++di; }
    }
  }

  // ---- fold partials across the quartet; thread qtr keeps dims [8*qtr, 8*qtr+8) ----
  // stage 1 (xor 2): pairs (0,2),(1,3); low pair keeps dims 0..15, high keeps 16..31
  float c[16];
  const bool hi2 = (qtr & 2) != 0;
#pragma unroll
  for (int i = 0; i < 16; ++i) {
    const float send = hi2 ? o[i] : o[i + 16];
    const float recv = __shfl_xor(send, 2, 64);
    const float keep = hi2 ? o[i + 16] : o[i];
    c[i] = keep + recv;
  }
  // stage 2 (xor 1): pairs (0,1),(2,3); even keeps c[0..7], odd keeps c[8..15]
  const bool hi1 = (qtr & 1) != 0;
  float of[8];
#pragma unroll
  for (int i = 0; i < 8; ++i) {
    const float send = hi1 ? c[i] : c[i + 8];
    const float recv = __shfl_xor(send, 1, 64);
    const float keep = hi1 ? c[i + 8] : c[i];
    of[i] = keep + recv;
  }

  half8 r0;
#pragma unroll
  for (int e = 0; e < 8; ++e) r0[e] = (_Float16)(of[e] * inv);
  *(half8*)(p.at16 + (size_t)n * 128 + h * 32 + qtr * 8) = r0;
}

// ---------------------------------------------------------------------------
// K3: projection GEMM (unchanged): block-local Wproj->fp16, A from global.
// ---------------------------------------------------------------------------
__global__ __launch_bounds__(256) void gemm2_kernel(Params p) {
  __shared__ __align__(16) _Float16 wsh[64 * WSTRIDE];
  const int tid = threadIdx.x;
  const int m0 = blockIdx.x * 64;
  const int n0 = blockIdx.y * 64;

  stage_rows_f16(p.Wproj + (size_t)n0 * 128, wsh, tid);
  __syncthreads();

  const int lane = tid & 63;
  const int w = tid >> 6;
  const int r = lane & 15;
  const int quad = lane >> 4;
  const _Float16* ap = p.at16 + (size_t)(m0 + w * 16 + r) * 128 + quad * 8;
  const _Float16* bp = wsh + r * WSTRIDE + quad * 8;

  floatx4 acc0 = {0.f, 0.f, 0.f, 0.f};
  floatx4 acc1 = acc0, acc2 = acc0, acc3 = acc0;
#pragma unroll
  for (int kc = 0; kc < 4; ++kc) {
    const half8 a  = *(const half8*)(ap + kc * 32);
    const half8 b0 = *(const half8*)(bp + kc * 32);
    const half8 b1 = *(const half8*)(bp + 16 * WSTRIDE + kc * 32);
    const half8 b2 = *(const half8*)(bp + 32 * WSTRIDE + kc * 32);
    const half8 b3 = *(const half8*)(bp + 48 * WSTRIDE + kc * 32);
    acc0 = __builtin_amdgcn_mfma_f32_16x16x32_f16(a, b0, acc0, 0, 0, 0);
    acc1 = __builtin_amdgcn_mfma_f32_16x16x32_f16(a, b1, acc1, 0, 0, 0);
    acc2 = __builtin_amdgcn_mfma_f32_16x16x32_f16(a, b2, acc2, 0, 0, 0);
    acc3 = __builtin_amdgcn_mfma_f32_16x16x32_f16(a, b3, acc3, 0, 0, 0);
  }

  const int mbase = m0 + w * 16 + quad * 4;
  floatx4 accs[4] = {acc0, acc1, acc2, acc3};
#pragma unroll
  for (int nt = 0; nt < 4; ++nt) {
    const int n = n0 + nt * 16 + r;
    const float bv = p.bproj[n];
    float* cp = p.out + (size_t)mbase * 128 + n;
#pragma unroll
    for (int reg = 0; reg < 4; ++reg)
      cp[(size_t)reg * 128] = accs[nt][reg] + bv;
  }
}

// ---------------------------------------------------------------------------
// Workspace (18 MB):
//   [1 MB, 13 MB)   qkv16  [3][16384][128] fp16 planar
//   [14 MB, 18 MB)  at16   [16384][128] fp16
// ---------------------------------------------------------------------------
extern "C" void kernel_launch(void* const* d_in, const int* in_sizes, int n_in,
                              void* d_out, int out_size, void* d_ws, size_t ws_size,
                              hipStream_t stream) {
  char* ws = (char*)d_ws;
  Params hp;
  hp.x     = (const float*)d_in[0];
  hp.ctx   = (const float*)d_in[1];
  hp.Wqkv  = (const float*)d_in[2];
  hp.bqkv  = (const float*)d_in[3];
  hp.A     = (const float*)d_in[4];
  hp.Blora = (const float*)d_in[5];
  hp.Vlora = (const float*)d_in[6];
  hp.g1w   = (const float*)d_in[7];
  hp.g1b   = (const float*)d_in[8];
  hp.g2w   = (const float*)d_in[9];
  hp.g2b   = (const float*)d_in[10];
  hp.Wproj = (const float*)d_in[11];
  hp.bproj = (const float*)d_in[12];
  hp.out   = (float*)d_out;
  hp.qkv16 = (_Float16*)(ws + (1u << 20));
  hp.at16  = (_Float16*)(ws + (14u << 20));

  gemm1_kernel<<<dim3(64, 2, 4), 256, 0, stream>>>(hp);
  attn_kernel<<<1024, 256, 0, stream>>>(hp);
  gemm2_kernel<<<dim3(256, 2), 256, 0, stream>>>(hp);
}